// Round 9
// baseline (372.882 us; speedup 1.0000x reference)
//
#include <hip/hip_runtime.h>
#include <math.h>

#define NC 40962
#define NF 163842
#define EPSV 1e-5f
#define LSLOPE 0.2f
#define NBLK 2561           // ceil(NF/64)

typedef __attribute__((ext_vector_type(8))) short bf16x8;
typedef __attribute__((ext_vector_type(4))) float f32x4;
typedef unsigned short u16;

#define MFMA(a,b,c) __builtin_amdgcn_mfma_f32_16x16x32_bf16(a,b,c,0,0,0)

__device__ __forceinline__ u16 f2bf(float f){
  unsigned u = __float_as_uint(f);
  u += 0x7fffu + ((u >> 16) & 1u);
  return (u16)(u >> 16);
}
__device__ __forceinline__ float bf2f(u16 h){ return __uint_as_float(((unsigned)h) << 16); }
__device__ __forceinline__ float lrelu(float v){ return v > 0.f ? v : LSLOPE * v; }

// ---------------- W converts fused: f32 -> bf16 for Wup, W1, W2 ----------------
__global__ void k_wcvt(const float* __restrict__ a, u16* __restrict__ da,
                       const float* __restrict__ b, u16* __restrict__ db,
                       const float* __restrict__ c, u16* __restrict__ dc){
  int i = blockIdx.x * 256 + threadIdx.x;
  const float* s; u16* d; int k;
  if (i < 7168)       { s = a; d = da; k = i; }
  else if (i < 14336) { s = b; d = db; k = i - 7168; }
  else if (i < 17920) { s = c; d = dc; k = i - 14336; }
  else return;
  const float4* sp = (const float4*)(s + (size_t)k * 8);
  float4 x = sp[0], y = sp[1];
  bf16x8 v;
  v[0]=(short)f2bf(x.x); v[1]=(short)f2bf(x.y); v[2]=(short)f2bf(x.z); v[3]=(short)f2bf(x.w);
  v[4]=(short)f2bf(y.x); v[5]=(short)f2bf(y.y); v[6]=(short)f2bf(y.z); v[7]=(short)f2bf(y.w);
  *(bf16x8*)(d + (size_t)k * 8) = v;
}

// ---------------- K1: upconv MFMA GEMM, A from x1 f32 directly, B from global ----------------
__global__ __launch_bounds__(256) void k_upconv(const float* __restrict__ x1,
                                                const u16* __restrict__ Wupb,
                                                const float* __restrict__ bup,
                                                u16* __restrict__ h){
  __shared__ __align__(16) unsigned char smem[34816];
  u16* As = (u16*)smem;               // [128][136] bf16
  float* Cs = (float*)smem;           // [128][68] f32 (after compute)
  const int t = threadIdx.x, l = t & 63, w = t >> 6;
  const int nn = t >> 1, half = t & 1;
  const int tile = blockIdx.x / 7, ot = blockIdx.x % 7;
  {
    int row = tile * 128 + nn; if (row >= NC) row = NC - 1;
    const float4* sp = (const float4*)(x1 + (size_t)row * 128 + half * 64);
#pragma unroll
    for (int c2 = 0; c2 < 8; ++c2) {
      float4 ga = sp[c2 * 2], gb = sp[c2 * 2 + 1];
      bf16x8 v;
      v[0]=(short)f2bf(ga.x); v[1]=(short)f2bf(ga.y); v[2]=(short)f2bf(ga.z); v[3]=(short)f2bf(ga.w);
      v[4]=(short)f2bf(gb.x); v[5]=(short)f2bf(gb.y); v[6]=(short)f2bf(gb.z); v[7]=(short)f2bf(gb.w);
      *(bf16x8*)(As + nn * 136 + half * 64 + c2 * 8) = v;
    }
  }
  float bias[4];
#pragma unroll
  for (int nt = 0; nt < 4; ++nt) bias[nt] = bup[ot * 64 + nt * 16 + (l & 15)];
  __syncthreads();
  f32x4 acc[2][4];
#pragma unroll
  for (int m = 0; m < 2; ++m)
#pragma unroll
    for (int nt = 0; nt < 4; ++nt) { acc[m][nt][0]=0.f; acc[m][nt][1]=0.f; acc[m][nt][2]=0.f; acc[m][nt][3]=0.f; }
  const u16* pA = As + (w * 32 + (l & 15)) * 136 + (l >> 4) * 8;
  const u16* wl = Wupb + (size_t)(ot * 64 + (l & 15)) * 128 + (l >> 4) * 8;
#pragma unroll
  for (int kk = 0; kk < 4; ++kk) {
    bf16x8 a0 = *(const bf16x8*)(pA + kk * 32);
    bf16x8 a1 = *(const bf16x8*)(pA + 16 * 136 + kk * 32);
#pragma unroll
    for (int nt = 0; nt < 4; ++nt) {
      bf16x8 b = *(const bf16x8*)(wl + nt * 16 * 128 + kk * 32);
      acc[0][nt] = MFMA(a0, b, acc[0][nt]);
      acc[1][nt] = MFMA(a1, b, acc[1][nt]);
    }
  }
  __syncthreads();
#pragma unroll
  for (int m = 0; m < 2; ++m)
#pragma unroll
    for (int nt = 0; nt < 4; ++nt)
#pragma unroll
      for (int r = 0; r < 4; ++r) {
        int rl = w * 32 + m * 16 + (l >> 4) * 4 + r;
        Cs[rl * 68 + nt * 16 + (l & 15)] = acc[m][nt][r] + bias[nt];
      }
  __syncthreads();
  {
    int node = tile * 128 + nn;
    if (node < NC) {
      u16* dst = h + (size_t)(7 * node + ot) * 64 + half * 32;
      const float* cp = Cs + nn * 68 + half * 32;
#pragma unroll
      for (int u = 0; u < 4; ++u) {
        bf16x8 v;
#pragma unroll
        for (int e = 0; e < 8; ++e) v[e] = (short)f2bf(cp[u * 8 + e]);
        *(bf16x8*)(dst + u * 8) = v;
      }
    }
  }
}

// ---------------- K2: x = concat([x1u, x2],1) as bf16 ----------------
__global__ void k_build_x(const u16* __restrict__ h, const float* __restrict__ x2,
                          const int* __restrict__ topi, const int* __restrict__ downi,
                          u16* __restrict__ x){
  int gid = blockIdx.x * 256 + threadIdx.x;
  if (gid >= NF * 16) return;
  int n = gid >> 4, q = gid & 15;
  u16* dst = x + (size_t)n * 128 + q * 8;
  if (q >= 8) {
    const float4* sp = (const float4*)(x2 + (size_t)n * 64 + (q - 8) * 8);
    float4 a = sp[0], b = sp[1];
    bf16x8 v;
    v[0]=(short)f2bf(a.x); v[1]=(short)f2bf(a.y); v[2]=(short)f2bf(a.z); v[3]=(short)f2bf(a.w);
    v[4]=(short)f2bf(b.x); v[5]=(short)f2bf(b.y); v[6]=(short)f2bf(b.z); v[7]=(short)f2bf(b.w);
    *(bf16x8*)dst = v;
  } else if (n < NC) {
    int r = topi[n];
    *(int4*)dst = *(const int4*)(h + (size_t)r * 64 + q * 8);
  } else {
    int i = n - NC, hi = (q >= 4) ? 1 : 0;
    int r = downi[2 * i + hi];
    const u16* sp = h + (size_t)r * 64 + 16 * q - 64 * hi;
    bf16x8 v;
#pragma unroll
    for (int e = 0; e < 8; ++e)
      v[e] = (short)f2bf(0.5f * (bf2f(sp[2 * e]) + bf2f(sp[2 * e + 1])));
    *(bf16x8*)dst = v;
  }
}

// ---------------- K3: conv1 — 28 gather loads pinned in flight via sched_barrier ----------------
__global__ __launch_bounds__(256, 3) void k_conv1(const u16* __restrict__ xb,
                                                  const int* __restrict__ neigh,
                                                  const u16* __restrict__ W1b,
                                                  const float* __restrict__ b1,
                                                  u16* __restrict__ yb,
                                                  float* __restrict__ psum,
                                                  float* __restrict__ psq){
  __shared__ __align__(16) unsigned char smem[25600];
  float* Cs = (float*)smem;            // [64][68]
  float* Ss = (float*)(smem + 17408);  // [16][64]
  float* Qs = (float*)(smem + 21504);
  const int t = threadIdx.x, l = t & 63, w = t >> 6;
  const int i = l & 15, g = l >> 4;
  const int n0 = blockIdx.x * 64;
  const int node = n0 + w * 16 + i;
  const int na = node < NF ? node : NF - 1;
  int idx[7];
#pragma unroll
  for (int jj = 0; jj < 7; ++jj) idx[jj] = neigh[7 * na + jj];
  // issue all 28 gather loads; sched_barrier(0) forbids the compiler from
  // sinking them into the MFMA loop (r8: it did, VGPR=44, 1-deep pipeline)
  bf16x8 a[7][4];
#pragma unroll
  for (int j = 0; j < 7; ++j) {
    const u16* src = xb + (size_t)idx[j] * 128 + g * 8;
    a[j][0] = *(const bf16x8*)(src);
    a[j][1] = *(const bf16x8*)(src + 32);
    a[j][2] = *(const bf16x8*)(src + 64);
    a[j][3] = *(const bf16x8*)(src + 96);
  }
  __builtin_amdgcn_sched_barrier(0);
  const u16* wl = W1b + (size_t)i * 896 + g * 8;
  f32x4 acc[4];
#pragma unroll
  for (int nt = 0; nt < 4; ++nt) { acc[nt][0]=0.f; acc[nt][1]=0.f; acc[nt][2]=0.f; acc[nt][3]=0.f; }
  float bias[4];
#pragma unroll
  for (int nt = 0; nt < 4; ++nt) bias[nt] = b1[nt * 16 + i];
#pragma unroll
  for (int j = 0; j < 7; ++j) {
    const u16* wj = wl + j * 128;
#pragma unroll
    for (int nt = 0; nt < 4; ++nt) {
      const u16* bp = wj + nt * 14336;
      acc[nt] = MFMA(a[j][0], *(const bf16x8*)(bp),      acc[nt]);
      acc[nt] = MFMA(a[j][1], *(const bf16x8*)(bp + 32), acc[nt]);
      acc[nt] = MFMA(a[j][2], *(const bf16x8*)(bp + 64), acc[nt]);
      acc[nt] = MFMA(a[j][3], *(const bf16x8*)(bp + 96), acc[nt]);
    }
  }
  float s[4] = {0.f,0.f,0.f,0.f}, q[4] = {0.f,0.f,0.f,0.f};
#pragma unroll
  for (int nt = 0; nt < 4; ++nt)
#pragma unroll
    for (int r = 0; r < 4; ++r) {
      int rl = w * 16 + g * 4 + r;
      float v = acc[nt][r] + bias[nt];
      Cs[rl * 68 + nt * 16 + i] = v;
      if (n0 + rl < NF) { s[nt] += v; q[nt] += v * v; }
    }
#pragma unroll
  for (int nt = 0; nt < 4; ++nt) {
    int id2 = (w * 4 + g) * 64 + nt * 16 + i;
    Ss[id2] = s[nt]; Qs[id2] = q[nt];
  }
  __syncthreads();
  {
    int row = t >> 2, part = t & 3;
    if (n0 + row < NF) {
      const float* cp = Cs + row * 68 + part * 16;
      u16* dst = yb + (size_t)(n0 + row) * 64 + part * 16;
      bf16x8 v0, v1;
#pragma unroll
      for (int e = 0; e < 8; ++e) { v0[e] = (short)f2bf(cp[e]); v1[e] = (short)f2bf(cp[8 + e]); }
      *(bf16x8*)dst = v0; *(bf16x8*)(dst + 8) = v1;
    }
  }
  if (t < 64) {
    float S = 0.f, Q = 0.f;
#pragma unroll
    for (int rr = 0; rr < 16; ++rr) { S += Ss[rr * 64 + t]; Q += Qs[rr * 64 + t]; }
    psum[blockIdx.x * 64 + t] = S;
    psq [blockIdx.x * 64 + t] = Q;
  }
}

// ---------------- K4a: BN partial tree-reduce  [nblk][64] -> [32][64] ----------------
__global__ __launch_bounds__(256) void k_statsA(const float* __restrict__ ps,
                                                const float* __restrict__ pq,
                                                int nblk,
                                                float* __restrict__ os,
                                                float* __restrict__ oq){
  __shared__ float sh[8][64];
  const int t = threadIdx.x, c = t & 63, r = t >> 6;
  float S = 0.f, Q = 0.f;
  for (int b = blockIdx.x * 4 + r; b < nblk; b += 128) { S += ps[b * 64 + c]; Q += pq[b * 64 + c]; }
  sh[r][c] = S; sh[4 + r][c] = Q;
  __syncthreads();
  if (t < 64) {
    os[blockIdx.x * 64 + t] = sh[0][t] + sh[1][t] + sh[2][t] + sh[3][t];
    oq[blockIdx.x * 64 + t] = sh[4][t] + sh[5][t] + sh[6][t] + sh[7][t];
  }
}

// ---------------- K4b: BN stats finalize (reads 32 rows) ----------------
__global__ __launch_bounds__(256) void k_stats(const float* __restrict__ ps,
                                               const float* __restrict__ pq,
                                               int nblk,
                                               const float* __restrict__ g,
                                               const float* __restrict__ beta,
                                               float* __restrict__ st){
  __shared__ float sh[8][64];
  const int t = threadIdx.x, c = t & 63, r = t >> 6;
  float S = 0.f, Q = 0.f;
  for (int b = r; b < nblk; b += 4) { S += ps[b * 64 + c]; Q += pq[b * 64 + c]; }
  sh[r][c] = S; sh[4 + r][c] = Q;
  __syncthreads();
  if (t < 64) {
    float Ss = sh[0][t] + sh[1][t] + sh[2][t] + sh[3][t];
    float Qs = sh[4][t] + sh[5][t] + sh[6][t] + sh[7][t];
    float mean = Ss * (1.f / (float)NF);
    float var  = Qs * (1.f / (float)NF) - mean * mean;
    var = var < 0.f ? 0.f : var;
    float scale = g[t] * rsqrtf(var + EPSV);
    st[t] = scale;
    st[64 + t] = beta[t] - mean * scale;
  }
}

// ---------------- K4c: y2 = lrelu(BN1(y)) once per node (bf16->bf16) ----------------
__global__ void k_bn1(const u16* __restrict__ y, const float* __restrict__ st1,
                      u16* __restrict__ y2){
  int gid = blockIdx.x * 256 + threadIdx.x;
  if (gid >= NF * 8) return;
  int q = gid & 7;
  int4 raw = *(const int4*)(y + (size_t)gid * 8);
  const u16* pr = (const u16*)&raw;
  bf16x8 v;
#pragma unroll
  for (int e = 0; e < 8; ++e) {
    float f = bf2f(pr[e]) * st1[q * 8 + e] + st1[64 + q * 8 + e];
    v[e] = (short)f2bf(lrelu(f));
  }
  *(bf16x8*)(y2 + (size_t)gid * 8) = v;
}

// ---------------- K5: conv2 — 14 gather loads pinned in flight ----------------
__global__ __launch_bounds__(256, 4) void k_conv2(const u16* __restrict__ y2,
                                                  const int* __restrict__ neigh,
                                                  const u16* __restrict__ W2b,
                                                  const float* __restrict__ b2,
                                                  u16* __restrict__ op,
                                                  float* __restrict__ psum,
                                                  float* __restrict__ psq){
  __shared__ __align__(16) unsigned char smem[25600];
  float* Cs = (float*)smem;
  float* Ss = (float*)(smem + 17408);
  float* Qs = (float*)(smem + 21504);
  const int t = threadIdx.x, l = t & 63, w = t >> 6;
  const int i = l & 15, g = l >> 4;
  const int n0 = blockIdx.x * 64;
  const int node = n0 + w * 16 + i;
  const int na = node < NF ? node : NF - 1;
  int idx[7];
#pragma unroll
  for (int jj = 0; jj < 7; ++jj) idx[jj] = neigh[7 * na + jj];
  bf16x8 a[7][2];
#pragma unroll
  for (int j = 0; j < 7; ++j) {
    const u16* src = y2 + (size_t)idx[j] * 64 + g * 8;
    a[j][0] = *(const bf16x8*)(src);
    a[j][1] = *(const bf16x8*)(src + 32);
  }
  __builtin_amdgcn_sched_barrier(0);
  const u16* wl = W2b + (size_t)i * 448 + g * 8;
  f32x4 acc[4];
#pragma unroll
  for (int nt = 0; nt < 4; ++nt) { acc[nt][0]=0.f; acc[nt][1]=0.f; acc[nt][2]=0.f; acc[nt][3]=0.f; }
  float bias[4];
#pragma unroll
  for (int nt = 0; nt < 4; ++nt) bias[nt] = b2[nt * 16 + i];
#pragma unroll
  for (int j = 0; j < 7; ++j) {
    const u16* wj = wl + j * 64;
#pragma unroll
    for (int nt = 0; nt < 4; ++nt) {
      const u16* bp = wj + nt * 7168;
      acc[nt] = MFMA(a[j][0], *(const bf16x8*)(bp),      acc[nt]);
      acc[nt] = MFMA(a[j][1], *(const bf16x8*)(bp + 32), acc[nt]);
    }
  }
  float s[4] = {0.f,0.f,0.f,0.f}, q[4] = {0.f,0.f,0.f,0.f};
#pragma unroll
  for (int nt = 0; nt < 4; ++nt)
#pragma unroll
    for (int r = 0; r < 4; ++r) {
      int rl = w * 16 + g * 4 + r;
      float v = acc[nt][r] + bias[nt];
      Cs[rl * 68 + nt * 16 + i] = v;
      if (n0 + rl < NF) { s[nt] += v; q[nt] += v * v; }
    }
#pragma unroll
  for (int nt = 0; nt < 4; ++nt) {
    int id2 = (w * 4 + g) * 64 + nt * 16 + i;
    Ss[id2] = s[nt]; Qs[id2] = q[nt];
  }
  __syncthreads();
  {
    int row = t >> 2, part = t & 3;
    if (n0 + row < NF) {
      const float* cp = Cs + row * 68 + part * 16;
      u16* dst = op + (size_t)(n0 + row) * 64 + part * 16;
      bf16x8 v0, v1;
#pragma unroll
      for (int e = 0; e < 8; ++e) { v0[e] = (short)f2bf(cp[e]); v1[e] = (short)f2bf(cp[8 + e]); }
      *(bf16x8*)dst = v0; *(bf16x8*)(dst + 8) = v1;
    }
  }
  if (t < 64) {
    float S = 0.f, Q = 0.f;
#pragma unroll
    for (int rr = 0; rr < 16; ++rr) { S += Ss[rr * 64 + t]; Q += Qs[rr * 64 + t]; }
    psum[blockIdx.x * 64 + t] = S;
    psq [blockIdx.x * 64 + t] = Q;
  }
}

// ---------------- K6: apply BN2 + leaky (op bf16 -> out f32) ----------------
__global__ void k_apply(const u16* __restrict__ op, const float* __restrict__ st2,
                        float* __restrict__ out){
  int gid = blockIdx.x * blockDim.x + threadIdx.x;
  if (gid >= NF * 8) return;
  int q = gid & 7;
  int4 raw = *(const int4*)(op + (size_t)gid * 8);
  const u16* pr = (const u16*)&raw;
  float4 o0, o1;
#pragma unroll
  for (int e = 0; e < 8; ++e) {
    float v = bf2f(pr[e]) * st2[q * 8 + e] + st2[64 + q * 8 + e];
    if (e < 4) (&o0.x)[e] = lrelu(v); else (&o1.x)[e - 4] = lrelu(v);
  }
  float4* dst = (float4*)(out + (size_t)gid * 8);
  dst[0] = o0; dst[1] = o1;
}

extern "C" void kernel_launch(void* const* d_in, const int* in_sizes, int n_in,
                              void* d_out, int out_size, void* d_ws, size_t ws_size,
                              hipStream_t stream) {
  (void)in_sizes; (void)n_in; (void)out_size; (void)ws_size;
  const float* x1   = (const float*)d_in[0];
  const float* x2   = (const float*)d_in[1];
  const int*   topi = (const int*)d_in[2];
  const int*   downi= (const int*)d_in[3];
  const int*   neigh= (const int*)d_in[4];
  const float* Wup  = (const float*)d_in[5];
  const float* bup  = (const float*)d_in[6];
  const float* W1   = (const float*)d_in[7];
  const float* b1   = (const float*)d_in[8];
  const float* g1   = (const float*)d_in[9];
  const float* be1  = (const float*)d_in[10];
  const float* W2   = (const float*)d_in[11];
  const float* b2   = (const float*)d_in[12];
  const float* g2   = (const float*)d_in[13];
  const float* be2  = (const float*)d_in[14];
  float* out = (float*)d_out;

  char* ws = (char*)d_ws;
  u16*   h    = (u16*)(ws);                    // 7NC x 64 bf16 = 36,701,952 B
  u16*   op   = (u16*)(ws);                    // NF x 64 bf16 (aliases h; h dead post build_x)
  u16*   x    = (u16*)(ws + 36701952ull);      // NF x 128 bf16 = 41,943,552 B
  u16*   y2   = (u16*)(ws + 36701952ull);      // NF x 64 bf16 (aliases x; x dead post conv1)
  u16*   y    = (u16*)(ws + 78645504ull);      // NF x 64 bf16  = 20,971,776 B
  u16*   Wupb = (u16*)(ws + 99617280ull);      // 448x128 bf16
  u16*   W1b  = (u16*)(ws + 99731968ull);      // 64x896 bf16
  u16*   W2b  = (u16*)(ws + 99846656ull);      // 64x448 bf16
  float* p1s  = (float*)(ws + 99904000ull);    // NBLK*64 f32 = 655,616 B each
  float* p1q  = (float*)(ws + 100559616ull);
  float* p2s  = (float*)(ws + 101215232ull);
  float* p2q  = (float*)(ws + 101870848ull);
  float* st1  = (float*)(ws + 102526464ull);
  float* st2  = (float*)(ws + 102526976ull);
  float* r1s  = (float*)(ws + 102527488ull);   // [32][64] f32
  float* r1q  = (float*)(ws + 102535680ull);
  float* r2s  = (float*)(ws + 102543872ull);
  float* r2q  = (float*)(ws + 102552064ull);

  k_wcvt   <<<70, 256, 0, stream>>>(Wup, Wupb, W1, W1b, W2, W2b);
  k_upconv <<<321 * 7, 256, 0, stream>>>(x1, Wupb, bup, h);
  k_build_x<<<(NF * 16 + 255) / 256, 256, 0, stream>>>(h, x2, topi, downi, x);
  k_conv1  <<<NBLK, 256, 0, stream>>>(x, neigh, W1b, b1, y, p1s, p1q);
  k_statsA <<<32, 256, 0, stream>>>(p1s, p1q, NBLK, r1s, r1q);
  k_stats  <<<1, 256, 0, stream>>>(r1s, r1q, 32, g1, be1, st1);
  k_bn1    <<<(NF * 8 + 255) / 256, 256, 0, stream>>>(y, st1, y2);
  k_conv2  <<<NBLK, 256, 0, stream>>>(y2, neigh, W2b, b2, op, p2s, p2q);
  k_statsA <<<32, 256, 0, stream>>>(p2s, p2q, NBLK, r2s, r2q);
  k_stats  <<<1, 256, 0, stream>>>(r2s, r2q, 32, g2, be2, st2);
  k_apply  <<<(NF * 8 + 255) / 256, 256, 0, stream>>>(op, st2, out);
}

// Round 10
// 286.210 us; speedup vs baseline: 1.3028x; 1.3028x over previous
//
#include <hip/hip_runtime.h>
#include <math.h>

#define NC 40962
#define NF 163842
#define EPSV 1e-5f
#define LSLOPE 0.2f
#define NBLK 1281           // ceil(NF/128)

typedef __attribute__((ext_vector_type(8))) short bf16x8;
typedef __attribute__((ext_vector_type(4))) float f32x4;
typedef unsigned short u16;

#define MFMA(a,b,c) __builtin_amdgcn_mfma_f32_16x16x32_bf16(a,b,c,0,0,0)

__device__ __forceinline__ u16 f2bf(float f){
  unsigned u = __float_as_uint(f);
  u += 0x7fffu + ((u >> 16) & 1u);
  return (u16)(u >> 16);
}
__device__ __forceinline__ float bf2f(u16 h){ return __uint_as_float(((unsigned)h) << 16); }
__device__ __forceinline__ float lrelu(float v){ return v > 0.f ? v : LSLOPE * v; }

// ---------------- W converts fused: f32 -> bf16 for Wup, W1, W2 ----------------
__global__ void k_wcvt(const float* __restrict__ a, u16* __restrict__ da,
                       const float* __restrict__ b, u16* __restrict__ db,
                       const float* __restrict__ c, u16* __restrict__ dc){
  int i = blockIdx.x * 256 + threadIdx.x;
  const float* s; u16* d; int k;
  if (i < 7168)       { s = a; d = da; k = i; }
  else if (i < 14336) { s = b; d = db; k = i - 7168; }
  else if (i < 17920) { s = c; d = dc; k = i - 14336; }
  else return;
  const float4* sp = (const float4*)(s + (size_t)k * 8);
  float4 x = sp[0], y = sp[1];
  bf16x8 v;
  v[0]=(short)f2bf(x.x); v[1]=(short)f2bf(x.y); v[2]=(short)f2bf(x.z); v[3]=(short)f2bf(x.w);
  v[4]=(short)f2bf(y.x); v[5]=(short)f2bf(y.y); v[6]=(short)f2bf(y.z); v[7]=(short)f2bf(y.w);
  *(bf16x8*)(d + (size_t)k * 8) = v;
}

// ---------------- K1: upconv MFMA GEMM, A from x1 f32 directly, B from global ----------------
__global__ __launch_bounds__(256) void k_upconv(const float* __restrict__ x1,
                                                const u16* __restrict__ Wupb,
                                                const float* __restrict__ bup,
                                                u16* __restrict__ h){
  __shared__ __align__(16) unsigned char smem[34816];
  u16* As = (u16*)smem;               // [128][136] bf16
  float* Cs = (float*)smem;           // [128][68] f32 (after compute)
  const int t = threadIdx.x, l = t & 63, w = t >> 6;
  const int nn = t >> 1, half = t & 1;
  const int tile = blockIdx.x / 7, ot = blockIdx.x % 7;
  {
    int row = tile * 128 + nn; if (row >= NC) row = NC - 1;
    const float4* sp = (const float4*)(x1 + (size_t)row * 128 + half * 64);
#pragma unroll
    for (int c2 = 0; c2 < 8; ++c2) {
      float4 ga = sp[c2 * 2], gb = sp[c2 * 2 + 1];
      bf16x8 v;
      v[0]=(short)f2bf(ga.x); v[1]=(short)f2bf(ga.y); v[2]=(short)f2bf(ga.z); v[3]=(short)f2bf(ga.w);
      v[4]=(short)f2bf(gb.x); v[5]=(short)f2bf(gb.y); v[6]=(short)f2bf(gb.z); v[7]=(short)f2bf(gb.w);
      *(bf16x8*)(As + nn * 136 + half * 64 + c2 * 8) = v;
    }
  }
  float bias[4];
#pragma unroll
  for (int nt = 0; nt < 4; ++nt) bias[nt] = bup[ot * 64 + nt * 16 + (l & 15)];
  __syncthreads();
  f32x4 acc[2][4];
#pragma unroll
  for (int m = 0; m < 2; ++m)
#pragma unroll
    for (int nt = 0; nt < 4; ++nt) { acc[m][nt][0]=0.f; acc[m][nt][1]=0.f; acc[m][nt][2]=0.f; acc[m][nt][3]=0.f; }
  const u16* pA = As + (w * 32 + (l & 15)) * 136 + (l >> 4) * 8;
  const u16* wl = Wupb + (size_t)(ot * 64 + (l & 15)) * 128 + (l >> 4) * 8;
#pragma unroll
  for (int kk = 0; kk < 4; ++kk) {
    bf16x8 a0 = *(const bf16x8*)(pA + kk * 32);
    bf16x8 a1 = *(const bf16x8*)(pA + 16 * 136 + kk * 32);
#pragma unroll
    for (int nt = 0; nt < 4; ++nt) {
      bf16x8 b = *(const bf16x8*)(wl + nt * 16 * 128 + kk * 32);
      acc[0][nt] = MFMA(a0, b, acc[0][nt]);
      acc[1][nt] = MFMA(a1, b, acc[1][nt]);
    }
  }
  __syncthreads();
#pragma unroll
  for (int m = 0; m < 2; ++m)
#pragma unroll
    for (int nt = 0; nt < 4; ++nt)
#pragma unroll
      for (int r = 0; r < 4; ++r) {
        int rl = w * 32 + m * 16 + (l >> 4) * 4 + r;
        Cs[rl * 68 + nt * 16 + (l & 15)] = acc[m][nt][r] + bias[nt];
      }
  __syncthreads();
  {
    int node = tile * 128 + nn;
    if (node < NC) {
      u16* dst = h + (size_t)(7 * node + ot) * 64 + half * 32;
      const float* cp = Cs + nn * 68 + half * 32;
#pragma unroll
      for (int u = 0; u < 4; ++u) {
        bf16x8 v;
#pragma unroll
        for (int e = 0; e < 8; ++e) v[e] = (short)f2bf(cp[u * 8 + e]);
        *(bf16x8*)(dst + u * 8) = v;
      }
    }
  }
}

// ---------------- K2: x = concat([x1u, x2],1) as bf16 ----------------
__global__ void k_build_x(const u16* __restrict__ h, const float* __restrict__ x2,
                          const int* __restrict__ topi, const int* __restrict__ downi,
                          u16* __restrict__ x){
  int gid = blockIdx.x * 256 + threadIdx.x;
  if (gid >= NF * 16) return;
  int n = gid >> 4, q = gid & 15;
  u16* dst = x + (size_t)n * 128 + q * 8;
  if (q >= 8) {
    const float4* sp = (const float4*)(x2 + (size_t)n * 64 + (q - 8) * 8);
    float4 a = sp[0], b = sp[1];
    bf16x8 v;
    v[0]=(short)f2bf(a.x); v[1]=(short)f2bf(a.y); v[2]=(short)f2bf(a.z); v[3]=(short)f2bf(a.w);
    v[4]=(short)f2bf(b.x); v[5]=(short)f2bf(b.y); v[6]=(short)f2bf(b.z); v[7]=(short)f2bf(b.w);
    *(bf16x8*)dst = v;
  } else if (n < NC) {
    int r = topi[n];
    *(int4*)dst = *(const int4*)(h + (size_t)r * 64 + q * 8);
  } else {
    int i = n - NC, hi = (q >= 4) ? 1 : 0;
    int r = downi[2 * i + hi];
    const u16* sp = h + (size_t)r * 64 + 16 * q - 64 * hi;
    bf16x8 v;
#pragma unroll
    for (int e = 0; e < 8; ++e)
      v[e] = (short)f2bf(0.5f * (bf2f(sp[2 * e]) + bf2f(sp[2 * e + 1])));
    *(bf16x8*)dst = v;
  }
}

// ---------------- K3: conv1 — r4 structure (per-thread burst gather -> LDS), B from global ----------------
// LDS: As [128][136]u16 = 34816 (aliased by Cs [128][68]f32 post-loop; wave-stripe row-aligned, safe)
//      Ss @34816, Qs @38912. total 43008 -> 3 blocks/CU.
__global__ __launch_bounds__(256) void k_conv1(const u16* __restrict__ xb,
                                               const int* __restrict__ neigh,
                                               const u16* __restrict__ W1b,
                                               const float* __restrict__ b1,
                                               u16* __restrict__ yb,
                                               float* __restrict__ psum,
                                               float* __restrict__ psq){
  __shared__ __align__(16) unsigned char smem[43008];
  u16* As = (u16*)smem;
  float* Cs = (float*)smem;
  float* Ss = (float*)(smem + 34816);
  float* Qs = (float*)(smem + 38912);
  const int t = threadIdx.x, l = t & 63, w = t >> 6;
  const int nn = t >> 1, half = t & 1;
  const int n0 = blockIdx.x * 128;
  const int node_s = n0 + nn;
  const u16* wl = W1b + (size_t)(l & 15) * 896 + (l >> 4) * 8;
  f32x4 acc[2][4];
#pragma unroll
  for (int m = 0; m < 2; ++m)
#pragma unroll
    for (int nt = 0; nt < 4; ++nt) { acc[m][nt][0]=0.f; acc[m][nt][1]=0.f; acc[m][nt][2]=0.f; acc[m][nt][3]=0.f; }
  float bias[4];
#pragma unroll
  for (int nt = 0; nt < 4; ++nt) bias[nt] = b1[nt * 16 + (l & 15)];
  for (int j = 0; j < 7; ++j) {
    __syncthreads();                 // prev MFMA reads of As complete
    {
      int r = (node_s < NF) ? neigh[7 * node_s + j] : 0;
      const int4* gp = (const int4*)(xb + (size_t)r * 128 + half * 64);
#pragma unroll
      for (int u = 0; u < 8; ++u) *(int4*)(As + nn * 136 + half * 64 + u * 8) = gp[u];
    }
    __syncthreads();                 // As visible
    const u16* pA = As + (w * 32 + (l & 15)) * 136 + (l >> 4) * 8;
    const u16* wj = wl + j * 128;
#pragma unroll
    for (int kk = 0; kk < 4; ++kk) {
      bf16x8 a0 = *(const bf16x8*)(pA + kk * 32);
      bf16x8 a1 = *(const bf16x8*)(pA + 16 * 136 + kk * 32);
#pragma unroll
      for (int nt = 0; nt < 4; ++nt) {
        bf16x8 b = *(const bf16x8*)(wj + nt * 14336 + kk * 32);
        acc[0][nt] = MFMA(a0, b, acc[0][nt]);
        acc[1][nt] = MFMA(a1, b, acc[1][nt]);
      }
    }
  }
  __syncthreads();
  float s[4] = {0.f,0.f,0.f,0.f}, q[4] = {0.f,0.f,0.f,0.f};
#pragma unroll
  for (int m = 0; m < 2; ++m)
#pragma unroll
    for (int nt = 0; nt < 4; ++nt)
#pragma unroll
      for (int r = 0; r < 4; ++r) {
        int rl = w * 32 + m * 16 + (l >> 4) * 4 + r;
        float v = acc[m][nt][r] + bias[nt];
        Cs[rl * 68 + nt * 16 + (l & 15)] = v;
        if (n0 + rl < NF) { s[nt] += v; q[nt] += v * v; }
      }
#pragma unroll
  for (int nt = 0; nt < 4; ++nt) {
    int idx = (w * 4 + (l >> 4)) * 64 + nt * 16 + (l & 15);
    Ss[idx] = s[nt]; Qs[idx] = q[nt];
  }
  __syncthreads();
  if (node_s < NF) {
    u16* dst = yb + (size_t)node_s * 64 + half * 32;
    const float* cp = Cs + nn * 68 + half * 32;
#pragma unroll
    for (int u = 0; u < 4; ++u) {
      bf16x8 v;
#pragma unroll
      for (int e = 0; e < 8; ++e) v[e] = (short)f2bf(cp[u * 8 + e]);
      *(bf16x8*)(dst + u * 8) = v;
    }
  }
  if (t < 64) {
    float S = 0.f, Q = 0.f;
#pragma unroll
    for (int rr = 0; rr < 16; ++rr) { S += Ss[rr * 64 + t]; Q += Qs[rr * 64 + t]; }
    psum[blockIdx.x * 64 + t] = S;
    psq [blockIdx.x * 64 + t] = Q;
  }
}

// ---------------- K4a: BN partial tree-reduce  [nblk][64] -> [32][64] ----------------
__global__ __launch_bounds__(256) void k_statsA(const float* __restrict__ ps,
                                                const float* __restrict__ pq,
                                                int nblk,
                                                float* __restrict__ os,
                                                float* __restrict__ oq){
  __shared__ float sh[8][64];
  const int t = threadIdx.x, c = t & 63, r = t >> 6;
  float S = 0.f, Q = 0.f;
  for (int b = blockIdx.x * 4 + r; b < nblk; b += 128) { S += ps[b * 64 + c]; Q += pq[b * 64 + c]; }
  sh[r][c] = S; sh[4 + r][c] = Q;
  __syncthreads();
  if (t < 64) {
    os[blockIdx.x * 64 + t] = sh[0][t] + sh[1][t] + sh[2][t] + sh[3][t];
    oq[blockIdx.x * 64 + t] = sh[4][t] + sh[5][t] + sh[6][t] + sh[7][t];
  }
}

// ---------------- K4b: BN stats finalize (reads 32 rows) ----------------
__global__ __launch_bounds__(256) void k_stats(const float* __restrict__ ps,
                                               const float* __restrict__ pq,
                                               int nblk,
                                               const float* __restrict__ g,
                                               const float* __restrict__ beta,
                                               float* __restrict__ st){
  __shared__ float sh[8][64];
  const int t = threadIdx.x, c = t & 63, r = t >> 6;
  float S = 0.f, Q = 0.f;
  for (int b = r; b < nblk; b += 4) { S += ps[b * 64 + c]; Q += pq[b * 64 + c]; }
  sh[r][c] = S; sh[4 + r][c] = Q;
  __syncthreads();
  if (t < 64) {
    float Ss = sh[0][t] + sh[1][t] + sh[2][t] + sh[3][t];
    float Qs = sh[4][t] + sh[5][t] + sh[6][t] + sh[7][t];
    float mean = Ss * (1.f / (float)NF);
    float var  = Qs * (1.f / (float)NF) - mean * mean;
    var = var < 0.f ? 0.f : var;
    float scale = g[t] * rsqrtf(var + EPSV);
    st[t] = scale;
    st[64 + t] = beta[t] - mean * scale;
  }
}

// ---------------- K4c: y2 = lrelu(BN1(y)) once per node (bf16->bf16) ----------------
__global__ void k_bn1(const u16* __restrict__ y, const float* __restrict__ st1,
                      u16* __restrict__ y2){
  int gid = blockIdx.x * 256 + threadIdx.x;
  if (gid >= NF * 8) return;
  int q = gid & 7;
  int4 raw = *(const int4*)(y + (size_t)gid * 8);
  const u16* pr = (const u16*)&raw;
  bf16x8 v;
#pragma unroll
  for (int e = 0; e < 8; ++e) {
    float f = bf2f(pr[e]) * st1[q * 8 + e] + st1[64 + q * 8 + e];
    v[e] = (short)f2bf(lrelu(f));
  }
  *(bf16x8*)(y2 + (size_t)gid * 8) = v;
}

// ---------------- K5: conv2 — r4 structure, B from global, clean gather from y2 ----------------
// LDS: As [128][72]u16 = 18432; Cs [128][68]f32 @0 (post-barrier); Ss @34816; Qs @38912.
__global__ __launch_bounds__(256) void k_conv2(const u16* __restrict__ y2,
                                               const int* __restrict__ neigh,
                                               const u16* __restrict__ W2b,
                                               const float* __restrict__ b2,
                                               u16* __restrict__ op,
                                               float* __restrict__ psum,
                                               float* __restrict__ psq){
  __shared__ __align__(16) unsigned char smem[43008];
  u16* As = (u16*)smem;
  float* Cs = (float*)smem;
  float* Ss = (float*)(smem + 34816);
  float* Qs = (float*)(smem + 38912);
  const int t = threadIdx.x, l = t & 63, w = t >> 6;
  const int nn = t >> 1, half = t & 1;
  const int n0 = blockIdx.x * 128;
  const int node_s = n0 + nn;
  const u16* wl = W2b + (size_t)(l & 15) * 448 + (l >> 4) * 8;
  f32x4 acc[2][4];
#pragma unroll
  for (int m = 0; m < 2; ++m)
#pragma unroll
    for (int nt = 0; nt < 4; ++nt) { acc[m][nt][0]=0.f; acc[m][nt][1]=0.f; acc[m][nt][2]=0.f; acc[m][nt][3]=0.f; }
  float bias[4];
#pragma unroll
  for (int nt = 0; nt < 4; ++nt) bias[nt] = b2[nt * 16 + (l & 15)];
  for (int j = 0; j < 7; ++j) {
    __syncthreads();
    {
      int r = (node_s < NF) ? neigh[7 * node_s + j] : 0;
      const int4* gp = (const int4*)(y2 + (size_t)r * 64 + half * 32);
#pragma unroll
      for (int u = 0; u < 4; ++u) *(int4*)(As + nn * 72 + half * 32 + u * 8) = gp[u];
    }
    __syncthreads();
    const u16* pA = As + (w * 32 + (l & 15)) * 72 + (l >> 4) * 8;
    const u16* wj = wl + j * 64;
#pragma unroll
    for (int kk = 0; kk < 2; ++kk) {
      bf16x8 a0 = *(const bf16x8*)(pA + kk * 32);
      bf16x8 a1 = *(const bf16x8*)(pA + 16 * 72 + kk * 32);
#pragma unroll
      for (int nt = 0; nt < 4; ++nt) {
        bf16x8 b = *(const bf16x8*)(wj + nt * 7168 + kk * 32);
        acc[0][nt] = MFMA(a0, b, acc[0][nt]);
        acc[1][nt] = MFMA(a1, b, acc[1][nt]);
      }
    }
  }
  __syncthreads();   // all As reads done before Cs overwrite (byte ranges cross waves here)
  float s[4] = {0.f,0.f,0.f,0.f}, q[4] = {0.f,0.f,0.f,0.f};
#pragma unroll
  for (int m = 0; m < 2; ++m)
#pragma unroll
    for (int nt = 0; nt < 4; ++nt)
#pragma unroll
      for (int r = 0; r < 4; ++r) {
        int rl = w * 32 + m * 16 + (l >> 4) * 4 + r;
        float v = acc[m][nt][r] + bias[nt];
        Cs[rl * 68 + nt * 16 + (l & 15)] = v;
        if (n0 + rl < NF) { s[nt] += v; q[nt] += v * v; }
      }
#pragma unroll
  for (int nt = 0; nt < 4; ++nt) {
    int idx = (w * 4 + (l >> 4)) * 64 + nt * 16 + (l & 15);
    Ss[idx] = s[nt]; Qs[idx] = q[nt];
  }
  __syncthreads();
  if (node_s < NF) {
    u16* dst = op + (size_t)node_s * 64 + half * 32;
    const float* cp = Cs + nn * 68 + half * 32;
#pragma unroll
    for (int u = 0; u < 4; ++u) {
      bf16x8 v;
#pragma unroll
      for (int e = 0; e < 8; ++e) v[e] = (short)f2bf(cp[u * 8 + e]);
      *(bf16x8*)(dst + u * 8) = v;
    }
  }
  if (t < 64) {
    float S = 0.f, Q = 0.f;
#pragma unroll
    for (int rr = 0; rr < 16; ++rr) { S += Ss[rr * 64 + t]; Q += Qs[rr * 64 + t]; }
    psum[blockIdx.x * 64 + t] = S;
    psq [blockIdx.x * 64 + t] = Q;
  }
}

// ---------------- K6: apply BN2 + leaky (op bf16 -> out f32) ----------------
__global__ void k_apply(const u16* __restrict__ op, const float* __restrict__ st2,
                        float* __restrict__ out){
  int gid = blockIdx.x * blockDim.x + threadIdx.x;
  if (gid >= NF * 8) return;
  int q = gid & 7;
  int4 raw = *(const int4*)(op + (size_t)gid * 8);
  const u16* pr = (const u16*)&raw;
  float4 o0, o1;
#pragma unroll
  for (int e = 0; e < 8; ++e) {
    float v = bf2f(pr[e]) * st2[q * 8 + e] + st2[64 + q * 8 + e];
    if (e < 4) (&o0.x)[e] = lrelu(v); else (&o1.x)[e - 4] = lrelu(v);
  }
  float4* dst = (float4*)(out + (size_t)gid * 8);
  dst[0] = o0; dst[1] = o1;
}

extern "C" void kernel_launch(void* const* d_in, const int* in_sizes, int n_in,
                              void* d_out, int out_size, void* d_ws, size_t ws_size,
                              hipStream_t stream) {
  (void)in_sizes; (void)n_in; (void)out_size; (void)ws_size;
  const float* x1   = (const float*)d_in[0];
  const float* x2   = (const float*)d_in[1];
  const int*   topi = (const int*)d_in[2];
  const int*   downi= (const int*)d_in[3];
  const int*   neigh= (const int*)d_in[4];
  const float* Wup  = (const float*)d_in[5];
  const float* bup  = (const float*)d_in[6];
  const float* W1   = (const float*)d_in[7];
  const float* b1   = (const float*)d_in[8];
  const float* g1   = (const float*)d_in[9];
  const float* be1  = (const float*)d_in[10];
  const float* W2   = (const float*)d_in[11];
  const float* b2   = (const float*)d_in[12];
  const float* g2   = (const float*)d_in[13];
  const float* be2  = (const float*)d_in[14];
  float* out = (float*)d_out;

  char* ws = (char*)d_ws;
  u16*   h    = (u16*)(ws);                    // 7NC x 64 bf16 = 36,701,952 B
  u16*   op   = (u16*)(ws);                    // NF x 64 bf16 (aliases h; h dead post build_x)
  u16*   x    = (u16*)(ws + 36701952ull);      // NF x 128 bf16 = 41,943,552 B
  u16*   y2   = (u16*)(ws + 36701952ull);      // NF x 64 bf16 (aliases x; x dead post conv1)
  u16*   y    = (u16*)(ws + 78645504ull);      // NF x 64 bf16  = 20,971,776 B
  u16*   Wupb = (u16*)(ws + 99617280ull);      // 448x128 bf16
  u16*   W1b  = (u16*)(ws + 99731968ull);      // 64x896 bf16
  u16*   W2b  = (u16*)(ws + 99846656ull);      // 64x448 bf16
  float* p1s  = (float*)(ws + 99904000ull);    // NBLK*64 f32 = 327,936 B each
  float* p1q  = (float*)(ws + 100231936ull);
  float* p2s  = (float*)(ws + 100559872ull);
  float* p2q  = (float*)(ws + 100887808ull);
  float* st1  = (float*)(ws + 101215744ull);
  float* st2  = (float*)(ws + 101216256ull);
  float* r1s  = (float*)(ws + 101216768ull);   // [32][64] f32
  float* r1q  = (float*)(ws + 101224960ull);
  float* r2s  = (float*)(ws + 101233152ull);
  float* r2q  = (float*)(ws + 101241344ull);

  k_wcvt   <<<70, 256, 0, stream>>>(Wup, Wupb, W1, W1b, W2, W2b);
  k_upconv <<<321 * 7, 256, 0, stream>>>(x1, Wupb, bup, h);
  k_build_x<<<(NF * 16 + 255) / 256, 256, 0, stream>>>(h, x2, topi, downi, x);
  k_conv1  <<<NBLK, 256, 0, stream>>>(x, neigh, W1b, b1, y, p1s, p1q);
  k_statsA <<<32, 256, 0, stream>>>(p1s, p1q, NBLK, r1s, r1q);
  k_stats  <<<1, 256, 0, stream>>>(r1s, r1q, 32, g1, be1, st1);
  k_bn1    <<<(NF * 8 + 255) / 256, 256, 0, stream>>>(y, st1, y2);
  k_conv2  <<<NBLK, 256, 0, stream>>>(y2, neigh, W2b, b2, op, p2s, p2q);
  k_statsA <<<32, 256, 0, stream>>>(p2s, p2q, NBLK, r2s, r2q);
  k_stats  <<<1, 256, 0, stream>>>(r2s, r2q, 32, g2, be2, st2);
  k_apply  <<<(NF * 8 + 255) / 256, 256, 0, stream>>>(op, st2, out);
}

// Round 11
// 210.621 us; speedup vs baseline: 1.7704x; 1.3589x over previous
//
#include <hip/hip_runtime.h>
#include <math.h>

#define NC 40962
#define NF 163842
#define EPSV 1e-5f
#define LSLOPE 0.2f
#define NBLK 1281           // ceil(NF/128)

typedef __attribute__((ext_vector_type(8))) short bf16x8;
typedef __attribute__((ext_vector_type(4))) float f32x4;
typedef unsigned short u16;

#define MFMA(a,b,c) __builtin_amdgcn_mfma_f32_16x16x32_bf16(a,b,c,0,0,0)

__device__ __forceinline__ u16 f2bf(float f){
  unsigned u = __float_as_uint(f);
  u += 0x7fffu + ((u >> 16) & 1u);
  return (u16)(u >> 16);
}
__device__ __forceinline__ float bf2f(u16 h){ return __uint_as_float(((unsigned)h) << 16); }
__device__ __forceinline__ float lrelu(float v){ return v > 0.f ? v : LSLOPE * v; }

// ---------------- W converts fused: f32 -> bf16 for Wup, W1, W2 ----------------
__global__ void k_wcvt(const float* __restrict__ a, u16* __restrict__ da,
                       const float* __restrict__ b, u16* __restrict__ db,
                       const float* __restrict__ c, u16* __restrict__ dc){
  int i = blockIdx.x * 256 + threadIdx.x;
  const float* s; u16* d; int k;
  if (i < 7168)       { s = a; d = da; k = i; }
  else if (i < 14336) { s = b; d = db; k = i - 7168; }
  else if (i < 17920) { s = c; d = dc; k = i - 14336; }
  else return;
  const float4* sp = (const float4*)(s + (size_t)k * 8);
  float4 x = sp[0], y = sp[1];
  bf16x8 v;
  v[0]=(short)f2bf(x.x); v[1]=(short)f2bf(x.y); v[2]=(short)f2bf(x.z); v[3]=(short)f2bf(x.w);
  v[4]=(short)f2bf(y.x); v[5]=(short)f2bf(y.y); v[6]=(short)f2bf(y.z); v[7]=(short)f2bf(y.w);
  *(bf16x8*)(d + (size_t)k * 8) = v;
}

// ---------------- K1: upconv MFMA GEMM, A from x1 f32 directly, B from global ----------------
__global__ __launch_bounds__(256) void k_upconv(const float* __restrict__ x1,
                                                const u16* __restrict__ Wupb,
                                                const float* __restrict__ bup,
                                                u16* __restrict__ h){
  __shared__ __align__(16) unsigned char smem[34816];
  u16* As = (u16*)smem;               // [128][136] bf16
  float* Cs = (float*)smem;           // [128][68] f32 (after compute)
  const int t = threadIdx.x, l = t & 63, w = t >> 6;
  const int nn = t >> 1, half = t & 1;
  const int tile = blockIdx.x / 7, ot = blockIdx.x % 7;
  {
    int row = tile * 128 + nn; if (row >= NC) row = NC - 1;
    const float4* sp = (const float4*)(x1 + (size_t)row * 128 + half * 64);
#pragma unroll
    for (int c2 = 0; c2 < 8; ++c2) {
      float4 ga = sp[c2 * 2], gb = sp[c2 * 2 + 1];
      bf16x8 v;
      v[0]=(short)f2bf(ga.x); v[1]=(short)f2bf(ga.y); v[2]=(short)f2bf(ga.z); v[3]=(short)f2bf(ga.w);
      v[4]=(short)f2bf(gb.x); v[5]=(short)f2bf(gb.y); v[6]=(short)f2bf(gb.z); v[7]=(short)f2bf(gb.w);
      *(bf16x8*)(As + nn * 136 + half * 64 + c2 * 8) = v;
    }
  }
  float bias[4];
#pragma unroll
  for (int nt = 0; nt < 4; ++nt) bias[nt] = bup[ot * 64 + nt * 16 + (l & 15)];
  __syncthreads();
  f32x4 acc[2][4];
#pragma unroll
  for (int m = 0; m < 2; ++m)
#pragma unroll
    for (int nt = 0; nt < 4; ++nt) { acc[m][nt][0]=0.f; acc[m][nt][1]=0.f; acc[m][nt][2]=0.f; acc[m][nt][3]=0.f; }
  const u16* pA = As + (w * 32 + (l & 15)) * 136 + (l >> 4) * 8;
  const u16* wl = Wupb + (size_t)(ot * 64 + (l & 15)) * 128 + (l >> 4) * 8;
#pragma unroll
  for (int kk = 0; kk < 4; ++kk) {
    bf16x8 a0 = *(const bf16x8*)(pA + kk * 32);
    bf16x8 a1 = *(const bf16x8*)(pA + 16 * 136 + kk * 32);
#pragma unroll
    for (int nt = 0; nt < 4; ++nt) {
      bf16x8 b = *(const bf16x8*)(wl + nt * 16 * 128 + kk * 32);
      acc[0][nt] = MFMA(a0, b, acc[0][nt]);
      acc[1][nt] = MFMA(a1, b, acc[1][nt]);
    }
  }
  __syncthreads();
#pragma unroll
  for (int m = 0; m < 2; ++m)
#pragma unroll
    for (int nt = 0; nt < 4; ++nt)
#pragma unroll
      for (int r = 0; r < 4; ++r) {
        int rl = w * 32 + m * 16 + (l >> 4) * 4 + r;
        Cs[rl * 68 + nt * 16 + (l & 15)] = acc[m][nt][r] + bias[nt];
      }
  __syncthreads();
  {
    int node = tile * 128 + nn;
    if (node < NC) {
      u16* dst = h + (size_t)(7 * node + ot) * 64 + half * 32;
      const float* cp = Cs + nn * 68 + half * 32;
#pragma unroll
      for (int u = 0; u < 4; ++u) {
        bf16x8 v;
#pragma unroll
        for (int e = 0; e < 8; ++e) v[e] = (short)f2bf(cp[u * 8 + e]);
        *(bf16x8*)(dst + u * 8) = v;
      }
    }
  }
}

// ---------------- K2: x = concat([x1u, x2],1) as bf16 ----------------
__global__ void k_build_x(const u16* __restrict__ h, const float* __restrict__ x2,
                          const int* __restrict__ topi, const int* __restrict__ downi,
                          u16* __restrict__ x){
  int gid = blockIdx.x * 256 + threadIdx.x;
  if (gid >= NF * 16) return;
  int n = gid >> 4, q = gid & 15;
  u16* dst = x + (size_t)n * 128 + q * 8;
  if (q >= 8) {
    const float4* sp = (const float4*)(x2 + (size_t)n * 64 + (q - 8) * 8);
    float4 a = sp[0], b = sp[1];
    bf16x8 v;
    v[0]=(short)f2bf(a.x); v[1]=(short)f2bf(a.y); v[2]=(short)f2bf(a.z); v[3]=(short)f2bf(a.w);
    v[4]=(short)f2bf(b.x); v[5]=(short)f2bf(b.y); v[6]=(short)f2bf(b.z); v[7]=(short)f2bf(b.w);
    *(bf16x8*)dst = v;
  } else if (n < NC) {
    int r = topi[n];
    *(int4*)dst = *(const int4*)(h + (size_t)r * 64 + q * 8);
  } else {
    int i = n - NC, hi = (q >= 4) ? 1 : 0;
    int r = downi[2 * i + hi];
    const u16* sp = h + (size_t)r * 64 + 16 * q - 64 * hi;
    bf16x8 v;
#pragma unroll
    for (int e = 0; e < 8; ++e)
      v[e] = (short)f2bf(0.5f * (bf2f(sp[2 * e]) + bf2f(sp[2 * e + 1])));
    *(bf16x8*)dst = v;
  }
}

// ---------------- K3: conv1 — r4-exact: A gather + B tile both LDS-staged ----------------
// LDS: As [128][136] u16 @0 (34816), Bs [64][136] u16 @34816 (17408) = 52224.
// Post-loop overlays: Cs [128][68] f32 @0; Ss @34816; Qs @38912.
__global__ __launch_bounds__(256) void k_conv1(const u16* __restrict__ xb,
                                               const int* __restrict__ neigh,
                                               const u16* __restrict__ W1b,
                                               const float* __restrict__ b1,
                                               u16* __restrict__ yb,
                                               float* __restrict__ psum,
                                               float* __restrict__ psq){
  __shared__ __align__(16) unsigned char smem[52224];
  u16* As = (u16*)smem;
  u16* Bs = (u16*)(smem + 34816);
  float* Cs = (float*)smem;
  float* Ss = (float*)(smem + 34816);
  float* Qs = (float*)(smem + 34816 + 4096);
  const int t = threadIdx.x, l = t & 63, w = t >> 6;
  const int nn = t >> 1, half = t & 1;
  const int n0 = blockIdx.x * 128;
  const int node_s = n0 + nn;
  f32x4 acc[2][4];
#pragma unroll
  for (int m = 0; m < 2; ++m)
#pragma unroll
    for (int nt = 0; nt < 4; ++nt) { acc[m][nt][0]=0.f; acc[m][nt][1]=0.f; acc[m][nt][2]=0.f; acc[m][nt][3]=0.f; }
  float bias[4];
#pragma unroll
  for (int nt = 0; nt < 4; ++nt) bias[nt] = b1[nt * 16 + (l & 15)];
  for (int j = 0; j < 7; ++j) {
    __syncthreads();
    {
      int r = (node_s < NF) ? neigh[7 * node_s + j] : 0;
      const int4* gp = (const int4*)(xb + (size_t)r * 128 + half * 64);
#pragma unroll
      for (int u = 0; u < 8; ++u) *(int4*)(As + nn * 136 + half * 64 + u * 8) = gp[u];
    }
    {
      int o = t & 63, ci = t >> 6;
      const int4* gp = (const int4*)(W1b + (size_t)o * 896 + j * 128 + ci * 32);
#pragma unroll
      for (int u = 0; u < 4; ++u) *(int4*)(Bs + o * 136 + ci * 32 + u * 8) = gp[u];
    }
    __syncthreads();
    const u16* pA = As + (w * 32 + (l & 15)) * 136 + (l >> 4) * 8;
    const u16* pB = Bs + (l & 15) * 136 + (l >> 4) * 8;
#pragma unroll
    for (int kk = 0; kk < 4; ++kk) {
      bf16x8 a0 = *(const bf16x8*)(pA + kk * 32);
      bf16x8 a1 = *(const bf16x8*)(pA + 16 * 136 + kk * 32);
#pragma unroll
      for (int nt = 0; nt < 4; ++nt) {
        bf16x8 b = *(const bf16x8*)(pB + nt * 16 * 136 + kk * 32);
        acc[0][nt] = MFMA(a0, b, acc[0][nt]);
        acc[1][nt] = MFMA(a1, b, acc[1][nt]);
      }
    }
  }
  __syncthreads();
  float s[4] = {0.f,0.f,0.f,0.f}, q[4] = {0.f,0.f,0.f,0.f};
#pragma unroll
  for (int m = 0; m < 2; ++m)
#pragma unroll
    for (int nt = 0; nt < 4; ++nt)
#pragma unroll
      for (int r = 0; r < 4; ++r) {
        int rl = w * 32 + m * 16 + (l >> 4) * 4 + r;
        float v = acc[m][nt][r] + bias[nt];
        Cs[rl * 68 + nt * 16 + (l & 15)] = v;
        if (n0 + rl < NF) { s[nt] += v; q[nt] += v * v; }
      }
#pragma unroll
  for (int nt = 0; nt < 4; ++nt) {
    int idx = (w * 4 + (l >> 4)) * 64 + nt * 16 + (l & 15);
    Ss[idx] = s[nt]; Qs[idx] = q[nt];
  }
  __syncthreads();
  if (node_s < NF) {
    u16* dst = yb + (size_t)node_s * 64 + half * 32;
    const float* cp = Cs + nn * 68 + half * 32;
#pragma unroll
    for (int u = 0; u < 4; ++u) {
      bf16x8 v;
#pragma unroll
      for (int e = 0; e < 8; ++e) v[e] = (short)f2bf(cp[u * 8 + e]);
      *(bf16x8*)(dst + u * 8) = v;
    }
  }
  if (t < 64) {
    float S = 0.f, Q = 0.f;
#pragma unroll
    for (int rr = 0; rr < 16; ++rr) { S += Ss[rr * 64 + t]; Q += Qs[rr * 64 + t]; }
    psum[blockIdx.x * 64 + t] = S;
    psq [blockIdx.x * 64 + t] = Q;
  }
}

// ---------------- K4a: BN partial tree-reduce  [nblk][64] -> [32][64] ----------------
__global__ __launch_bounds__(256) void k_statsA(const float* __restrict__ ps,
                                                const float* __restrict__ pq,
                                                int nblk,
                                                float* __restrict__ os,
                                                float* __restrict__ oq){
  __shared__ float sh[8][64];
  const int t = threadIdx.x, c = t & 63, r = t >> 6;
  float S = 0.f, Q = 0.f;
  for (int b = blockIdx.x * 4 + r; b < nblk; b += 128) { S += ps[b * 64 + c]; Q += pq[b * 64 + c]; }
  sh[r][c] = S; sh[4 + r][c] = Q;
  __syncthreads();
  if (t < 64) {
    os[blockIdx.x * 64 + t] = sh[0][t] + sh[1][t] + sh[2][t] + sh[3][t];
    oq[blockIdx.x * 64 + t] = sh[4][t] + sh[5][t] + sh[6][t] + sh[7][t];
  }
}

// ---------------- K4b: BN stats finalize (reads 32 rows) ----------------
__global__ __launch_bounds__(256) void k_stats(const float* __restrict__ ps,
                                               const float* __restrict__ pq,
                                               int nblk,
                                               const float* __restrict__ g,
                                               const float* __restrict__ beta,
                                               float* __restrict__ st){
  __shared__ float sh[8][64];
  const int t = threadIdx.x, c = t & 63, r = t >> 6;
  float S = 0.f, Q = 0.f;
  for (int b = r; b < nblk; b += 4) { S += ps[b * 64 + c]; Q += pq[b * 64 + c]; }
  sh[r][c] = S; sh[4 + r][c] = Q;
  __syncthreads();
  if (t < 64) {
    float Ss = sh[0][t] + sh[1][t] + sh[2][t] + sh[3][t];
    float Qs = sh[4][t] + sh[5][t] + sh[6][t] + sh[7][t];
    float mean = Ss * (1.f / (float)NF);
    float var  = Qs * (1.f / (float)NF) - mean * mean;
    var = var < 0.f ? 0.f : var;
    float scale = g[t] * rsqrtf(var + EPSV);
    st[t] = scale;
    st[64 + t] = beta[t] - mean * scale;
  }
}

// ---------------- K4c: y2 = lrelu(BN1(y)) once per node (bf16->bf16) ----------------
__global__ void k_bn1(const u16* __restrict__ y, const float* __restrict__ st1,
                      u16* __restrict__ y2){
  int gid = blockIdx.x * 256 + threadIdx.x;
  if (gid >= NF * 8) return;
  int q = gid & 7;
  int4 raw = *(const int4*)(y + (size_t)gid * 8);
  const u16* pr = (const u16*)&raw;
  bf16x8 v;
#pragma unroll
  for (int e = 0; e < 8; ++e) {
    float f = bf2f(pr[e]) * st1[q * 8 + e] + st1[64 + q * 8 + e];
    v[e] = (short)f2bf(lrelu(f));
  }
  *(bf16x8*)(y2 + (size_t)gid * 8) = v;
}

// ---------------- K5: conv2 — r4-exact staging (A+B in LDS), clean gather from y2 ----------------
// LDS: As [128][72] @0 (18432), Bs [64][72] @18432 (9216); post-loop Cs [128][68] @0;
// Ss @34816; Qs @38912. total 43008.
__global__ __launch_bounds__(256) void k_conv2(const u16* __restrict__ y2,
                                               const int* __restrict__ neigh,
                                               const u16* __restrict__ W2b,
                                               const float* __restrict__ b2,
                                               u16* __restrict__ op,
                                               float* __restrict__ psum,
                                               float* __restrict__ psq){
  __shared__ __align__(16) unsigned char smem[43008];
  u16* As = (u16*)smem;
  u16* Bs = (u16*)(smem + 18432);
  float* Cs = (float*)smem;
  float* Ss = (float*)(smem + 34816);
  float* Qs = (float*)(smem + 38912);
  const int t = threadIdx.x, l = t & 63, w = t >> 6;
  const int nn = t >> 1, half = t & 1;
  const int n0 = blockIdx.x * 128;
  const int node_s = n0 + nn;
  f32x4 acc[2][4];
#pragma unroll
  for (int m = 0; m < 2; ++m)
#pragma unroll
    for (int nt = 0; nt < 4; ++nt) { acc[m][nt][0]=0.f; acc[m][nt][1]=0.f; acc[m][nt][2]=0.f; acc[m][nt][3]=0.f; }
  float bias[4];
#pragma unroll
  for (int nt = 0; nt < 4; ++nt) bias[nt] = b2[nt * 16 + (l & 15)];
  for (int j = 0; j < 7; ++j) {
    __syncthreads();
    {
      int r = (node_s < NF) ? neigh[7 * node_s + j] : 0;
      const int4* gp = (const int4*)(y2 + (size_t)r * 64 + half * 32);
#pragma unroll
      for (int u = 0; u < 4; ++u) *(int4*)(As + nn * 72 + half * 32 + u * 8) = gp[u];
    }
    {
      int o = t & 63, ci = t >> 6;
      const int4* gp = (const int4*)(W2b + (size_t)o * 448 + j * 64 + ci * 16);
#pragma unroll
      for (int u = 0; u < 2; ++u) *(int4*)(Bs + o * 72 + ci * 16 + u * 8) = gp[u];
    }
    __syncthreads();
    const u16* pA = As + (w * 32 + (l & 15)) * 72 + (l >> 4) * 8;
    const u16* pB = Bs + (l & 15) * 72 + (l >> 4) * 8;
#pragma unroll
    for (int kk = 0; kk < 2; ++kk) {
      bf16x8 a0 = *(const bf16x8*)(pA + kk * 32);
      bf16x8 a1 = *(const bf16x8*)(pA + 16 * 72 + kk * 32);
#pragma unroll
      for (int nt = 0; nt < 4; ++nt) {
        bf16x8 b = *(const bf16x8*)(pB + nt * 16 * 72 + kk * 32);
        acc[0][nt] = MFMA(a0, b, acc[0][nt]);
        acc[1][nt] = MFMA(a1, b, acc[1][nt]);
      }
    }
  }
  __syncthreads();   // all As/Bs reads done before Cs overwrite
  float s[4] = {0.f,0.f,0.f,0.f}, q[4] = {0.f,0.f,0.f,0.f};
#pragma unroll
  for (int m = 0; m < 2; ++m)
#pragma unroll
    for (int nt = 0; nt < 4; ++nt)
#pragma unroll
      for (int r = 0; r < 4; ++r) {
        int rl = w * 32 + m * 16 + (l >> 4) * 4 + r;
        float v = acc[m][nt][r] + bias[nt];
        Cs[rl * 68 + nt * 16 + (l & 15)] = v;
        if (n0 + rl < NF) { s[nt] += v; q[nt] += v * v; }
      }
#pragma unroll
  for (int nt = 0; nt < 4; ++nt) {
    int idx = (w * 4 + (l >> 4)) * 64 + nt * 16 + (l & 15);
    Ss[idx] = s[nt]; Qs[idx] = q[nt];
  }
  __syncthreads();
  if (node_s < NF) {
    u16* dst = op + (size_t)node_s * 64 + half * 32;
    const float* cp = Cs + nn * 68 + half * 32;
#pragma unroll
    for (int u = 0; u < 4; ++u) {
      bf16x8 v;
#pragma unroll
      for (int e = 0; e < 8; ++e) v[e] = (short)f2bf(cp[u * 8 + e]);
      *(bf16x8*)(dst + u * 8) = v;
    }
  }
  if (t < 64) {
    float S = 0.f, Q = 0.f;
#pragma unroll
    for (int rr = 0; rr < 16; ++rr) { S += Ss[rr * 64 + t]; Q += Qs[rr * 64 + t]; }
    psum[blockIdx.x * 64 + t] = S;
    psq [blockIdx.x * 64 + t] = Q;
  }
}

// ---------------- K6: apply BN2 + leaky (op bf16 -> out f32) ----------------
__global__ void k_apply(const u16* __restrict__ op, const float* __restrict__ st2,
                        float* __restrict__ out){
  int gid = blockIdx.x * blockDim.x + threadIdx.x;
  if (gid >= NF * 8) return;
  int q = gid & 7;
  int4 raw = *(const int4*)(op + (size_t)gid * 8);
  const u16* pr = (const u16*)&raw;
  float4 o0, o1;
#pragma unroll
  for (int e = 0; e < 8; ++e) {
    float v = bf2f(pr[e]) * st2[q * 8 + e] + st2[64 + q * 8 + e];
    if (e < 4) (&o0.x)[e] = lrelu(v); else (&o1.x)[e - 4] = lrelu(v);
  }
  float4* dst = (float4*)(out + (size_t)gid * 8);
  dst[0] = o0; dst[1] = o1;
}

extern "C" void kernel_launch(void* const* d_in, const int* in_sizes, int n_in,
                              void* d_out, int out_size, void* d_ws, size_t ws_size,
                              hipStream_t stream) {
  (void)in_sizes; (void)n_in; (void)out_size; (void)ws_size;
  const float* x1   = (const float*)d_in[0];
  const float* x2   = (const float*)d_in[1];
  const int*   topi = (const int*)d_in[2];
  const int*   downi= (const int*)d_in[3];
  const int*   neigh= (const int*)d_in[4];
  const float* Wup  = (const float*)d_in[5];
  const float* bup  = (const float*)d_in[6];
  const float* W1   = (const float*)d_in[7];
  const float* b1   = (const float*)d_in[8];
  const float* g1   = (const float*)d_in[9];
  const float* be1  = (const float*)d_in[10];
  const float* W2   = (const float*)d_in[11];
  const float* b2   = (const float*)d_in[12];
  const float* g2   = (const float*)d_in[13];
  const float* be2  = (const float*)d_in[14];
  float* out = (float*)d_out;

  char* ws = (char*)d_ws;
  u16*   h    = (u16*)(ws);                    // 7NC x 64 bf16 = 36,701,952 B
  u16*   op   = (u16*)(ws);                    // NF x 64 bf16 (aliases h; h dead post build_x)
  u16*   x    = (u16*)(ws + 36701952ull);      // NF x 128 bf16 = 41,943,552 B
  u16*   y2   = (u16*)(ws + 36701952ull);      // NF x 64 bf16 (aliases x; x dead post conv1)
  u16*   y    = (u16*)(ws + 78645504ull);      // NF x 64 bf16  = 20,971,776 B
  u16*   Wupb = (u16*)(ws + 99617280ull);      // 448x128 bf16
  u16*   W1b  = (u16*)(ws + 99731968ull);      // 64x896 bf16
  u16*   W2b  = (u16*)(ws + 99846656ull);      // 64x448 bf16
  float* p1s  = (float*)(ws + 99904000ull);    // NBLK*64 f32 = 327,936 B each
  float* p1q  = (float*)(ws + 100231936ull);
  float* p2s  = (float*)(ws + 100559872ull);
  float* p2q  = (float*)(ws + 100887808ull);
  float* st1  = (float*)(ws + 101215744ull);
  float* st2  = (float*)(ws + 101216256ull);
  float* r1s  = (float*)(ws + 101216768ull);   // [32][64] f32
  float* r1q  = (float*)(ws + 101224960ull);
  float* r2s  = (float*)(ws + 101233152ull);
  float* r2q  = (float*)(ws + 101241344ull);

  k_wcvt   <<<70, 256, 0, stream>>>(Wup, Wupb, W1, W1b, W2, W2b);
  k_upconv <<<321 * 7, 256, 0, stream>>>(x1, Wupb, bup, h);
  k_build_x<<<(NF * 16 + 255) / 256, 256, 0, stream>>>(h, x2, topi, downi, x);
  k_conv1  <<<NBLK, 256, 0, stream>>>(x, neigh, W1b, b1, y, p1s, p1q);
  k_statsA <<<32, 256, 0, stream>>>(p1s, p1q, NBLK, r1s, r1q);
  k_stats  <<<1, 256, 0, stream>>>(r1s, r1q, 32, g1, be1, st1);
  k_bn1    <<<(NF * 8 + 255) / 256, 256, 0, stream>>>(y, st1, y2);
  k_conv2  <<<NBLK, 256, 0, stream>>>(y2, neigh, W2b, b2, op, p2s, p2q);
  k_statsA <<<32, 256, 0, stream>>>(p2s, p2q, NBLK, r2s, r2q);
  k_stats  <<<1, 256, 0, stream>>>(r2s, r2q, 32, g2, be2, st2);
  k_apply  <<<(NF * 8 + 255) / 256, 256, 0, stream>>>(op, st2, out);
}

// Round 12
// 208.702 us; speedup vs baseline: 1.7867x; 1.0092x over previous
//
#include <hip/hip_runtime.h>
#include <math.h>

#define NC 40962
#define NF 163842
#define EPSV 1e-5f
#define LSLOPE 0.2f
#define NBLK 1281           // ceil(NF/128)

typedef __attribute__((ext_vector_type(8))) short bf16x8;
typedef __attribute__((ext_vector_type(4))) float f32x4;
typedef unsigned short u16;

#define MFMA(a,b,c) __builtin_amdgcn_mfma_f32_16x16x32_bf16(a,b,c,0,0,0)

__device__ __forceinline__ u16 f2bf(float f){
  unsigned u = __float_as_uint(f);
  u += 0x7fffu + ((u >> 16) & 1u);
  return (u16)(u >> 16);
}
__device__ __forceinline__ float bf2f(u16 h){ return __uint_as_float(((unsigned)h) << 16); }
__device__ __forceinline__ float lrelu(float v){ return v > 0.f ? v : LSLOPE * v; }

// ---------------- W converts fused: f32 -> bf16 for Wup, W1, W2 ----------------
__global__ void k_wcvt(const float* __restrict__ a, u16* __restrict__ da,
                       const float* __restrict__ b, u16* __restrict__ db,
                       const float* __restrict__ c, u16* __restrict__ dc){
  int i = blockIdx.x * 256 + threadIdx.x;
  const float* s; u16* d; int k;
  if (i < 7168)       { s = a; d = da; k = i; }
  else if (i < 14336) { s = b; d = db; k = i - 7168; }
  else if (i < 17920) { s = c; d = dc; k = i - 14336; }
  else return;
  const float4* sp = (const float4*)(s + (size_t)k * 8);
  float4 x = sp[0], y = sp[1];
  bf16x8 v;
  v[0]=(short)f2bf(x.x); v[1]=(short)f2bf(x.y); v[2]=(short)f2bf(x.z); v[3]=(short)f2bf(x.w);
  v[4]=(short)f2bf(y.x); v[5]=(short)f2bf(y.y); v[6]=(short)f2bf(y.z); v[7]=(short)f2bf(y.w);
  *(bf16x8*)(d + (size_t)k * 8) = v;
}

// ---------------- K1: upconv MFMA GEMM, A from x1 f32 directly, B from global ----------------
__global__ __launch_bounds__(256) void k_upconv(const float* __restrict__ x1,
                                                const u16* __restrict__ Wupb,
                                                const float* __restrict__ bup,
                                                u16* __restrict__ h){
  __shared__ __align__(16) unsigned char smem[34816];
  u16* As = (u16*)smem;               // [128][136] bf16
  float* Cs = (float*)smem;           // [128][68] f32 (after compute)
  const int t = threadIdx.x, l = t & 63, w = t >> 6;
  const int nn = t >> 1, half = t & 1;
  const int tile = blockIdx.x / 7, ot = blockIdx.x % 7;
  {
    int row = tile * 128 + nn; if (row >= NC) row = NC - 1;
    const float4* sp = (const float4*)(x1 + (size_t)row * 128 + half * 64);
#pragma unroll
    for (int c2 = 0; c2 < 8; ++c2) {
      float4 ga = sp[c2 * 2], gb = sp[c2 * 2 + 1];
      bf16x8 v;
      v[0]=(short)f2bf(ga.x); v[1]=(short)f2bf(ga.y); v[2]=(short)f2bf(ga.z); v[3]=(short)f2bf(ga.w);
      v[4]=(short)f2bf(gb.x); v[5]=(short)f2bf(gb.y); v[6]=(short)f2bf(gb.z); v[7]=(short)f2bf(gb.w);
      *(bf16x8*)(As + nn * 136 + half * 64 + c2 * 8) = v;
    }
  }
  float bias[4];
#pragma unroll
  for (int nt = 0; nt < 4; ++nt) bias[nt] = bup[ot * 64 + nt * 16 + (l & 15)];
  __syncthreads();
  f32x4 acc[2][4];
#pragma unroll
  for (int m = 0; m < 2; ++m)
#pragma unroll
    for (int nt = 0; nt < 4; ++nt) { acc[m][nt][0]=0.f; acc[m][nt][1]=0.f; acc[m][nt][2]=0.f; acc[m][nt][3]=0.f; }
  const u16* pA = As + (w * 32 + (l & 15)) * 136 + (l >> 4) * 8;
  const u16* wl = Wupb + (size_t)(ot * 64 + (l & 15)) * 128 + (l >> 4) * 8;
#pragma unroll
  for (int kk = 0; kk < 4; ++kk) {
    bf16x8 a0 = *(const bf16x8*)(pA + kk * 32);
    bf16x8 a1 = *(const bf16x8*)(pA + 16 * 136 + kk * 32);
#pragma unroll
    for (int nt = 0; nt < 4; ++nt) {
      bf16x8 b = *(const bf16x8*)(wl + nt * 16 * 128 + kk * 32);
      acc[0][nt] = MFMA(a0, b, acc[0][nt]);
      acc[1][nt] = MFMA(a1, b, acc[1][nt]);
    }
  }
  __syncthreads();
#pragma unroll
  for (int m = 0; m < 2; ++m)
#pragma unroll
    for (int nt = 0; nt < 4; ++nt)
#pragma unroll
      for (int r = 0; r < 4; ++r) {
        int rl = w * 32 + m * 16 + (l >> 4) * 4 + r;
        Cs[rl * 68 + nt * 16 + (l & 15)] = acc[m][nt][r] + bias[nt];
      }
  __syncthreads();
  {
    int node = tile * 128 + nn;
    if (node < NC) {
      u16* dst = h + (size_t)(7 * node + ot) * 64 + half * 32;
      const float* cp = Cs + nn * 68 + half * 32;
#pragma unroll
      for (int u = 0; u < 4; ++u) {
        bf16x8 v;
#pragma unroll
        for (int e = 0; e < 8; ++e) v[e] = (short)f2bf(cp[u * 8 + e]);
        *(bf16x8*)(dst + u * 8) = v;
      }
    }
  }
}

// ---------------- K2: x = concat([x1u, x2],1) as bf16 ----------------
__global__ void k_build_x(const u16* __restrict__ h, const float* __restrict__ x2,
                          const int* __restrict__ topi, const int* __restrict__ downi,
                          u16* __restrict__ x){
  int gid = blockIdx.x * 256 + threadIdx.x;
  if (gid >= NF * 16) return;
  int n = gid >> 4, q = gid & 15;
  u16* dst = x + (size_t)n * 128 + q * 8;
  if (q >= 8) {
    const float4* sp = (const float4*)(x2 + (size_t)n * 64 + (q - 8) * 8);
    float4 a = sp[0], b = sp[1];
    bf16x8 v;
    v[0]=(short)f2bf(a.x); v[1]=(short)f2bf(a.y); v[2]=(short)f2bf(a.z); v[3]=(short)f2bf(a.w);
    v[4]=(short)f2bf(b.x); v[5]=(short)f2bf(b.y); v[6]=(short)f2bf(b.z); v[7]=(short)f2bf(b.w);
    *(bf16x8*)dst = v;
  } else if (n < NC) {
    int r = topi[n];
    *(int4*)dst = *(const int4*)(h + (size_t)r * 64 + q * 8);
  } else {
    int i = n - NC, hi = (q >= 4) ? 1 : 0;
    int r = downi[2 * i + hi];
    const u16* sp = h + (size_t)r * 64 + 16 * q - 64 * hi;
    bf16x8 v;
#pragma unroll
    for (int e = 0; e < 8; ++e)
      v[e] = (short)f2bf(0.5f * (bf2f(sp[2 * e]) + bf2f(sp[2 * e + 1])));
    *(bf16x8*)dst = v;
  }
}

// ---------------- K3: conv1 — burst gather + B tile both LDS-staged (measured-best) ----------------
__global__ __launch_bounds__(256) void k_conv1(const u16* __restrict__ xb,
                                               const int* __restrict__ neigh,
                                               const u16* __restrict__ W1b,
                                               const float* __restrict__ b1,
                                               u16* __restrict__ yb,
                                               float* __restrict__ psum,
                                               float* __restrict__ psq){
  __shared__ __align__(16) unsigned char smem[52224];
  u16* As = (u16*)smem;
  u16* Bs = (u16*)(smem + 34816);
  float* Cs = (float*)smem;
  float* Ss = (float*)(smem + 34816);
  float* Qs = (float*)(smem + 34816 + 4096);
  const int t = threadIdx.x, l = t & 63, w = t >> 6;
  const int nn = t >> 1, half = t & 1;
  const int n0 = blockIdx.x * 128;
  const int node_s = n0 + nn;
  f32x4 acc[2][4];
#pragma unroll
  for (int m = 0; m < 2; ++m)
#pragma unroll
    for (int nt = 0; nt < 4; ++nt) { acc[m][nt][0]=0.f; acc[m][nt][1]=0.f; acc[m][nt][2]=0.f; acc[m][nt][3]=0.f; }
  float bias[4];
#pragma unroll
  for (int nt = 0; nt < 4; ++nt) bias[nt] = b1[nt * 16 + (l & 15)];
  for (int j = 0; j < 7; ++j) {
    __syncthreads();
    {
      int r = (node_s < NF) ? neigh[7 * node_s + j] : 0;
      const int4* gp = (const int4*)(xb + (size_t)r * 128 + half * 64);
#pragma unroll
      for (int u = 0; u < 8; ++u) *(int4*)(As + nn * 136 + half * 64 + u * 8) = gp[u];
    }
    {
      int o = t & 63, ci = t >> 6;
      const int4* gp = (const int4*)(W1b + (size_t)o * 896 + j * 128 + ci * 32);
#pragma unroll
      for (int u = 0; u < 4; ++u) *(int4*)(Bs + o * 136 + ci * 32 + u * 8) = gp[u];
    }
    __syncthreads();
    const u16* pA = As + (w * 32 + (l & 15)) * 136 + (l >> 4) * 8;
    const u16* pB = Bs + (l & 15) * 136 + (l >> 4) * 8;
#pragma unroll
    for (int kk = 0; kk < 4; ++kk) {
      bf16x8 a0 = *(const bf16x8*)(pA + kk * 32);
      bf16x8 a1 = *(const bf16x8*)(pA + 16 * 136 + kk * 32);
#pragma unroll
      for (int nt = 0; nt < 4; ++nt) {
        bf16x8 b = *(const bf16x8*)(pB + nt * 16 * 136 + kk * 32);
        acc[0][nt] = MFMA(a0, b, acc[0][nt]);
        acc[1][nt] = MFMA(a1, b, acc[1][nt]);
      }
    }
  }
  __syncthreads();
  float s[4] = {0.f,0.f,0.f,0.f}, q[4] = {0.f,0.f,0.f,0.f};
#pragma unroll
  for (int m = 0; m < 2; ++m)
#pragma unroll
    for (int nt = 0; nt < 4; ++nt)
#pragma unroll
      for (int r = 0; r < 4; ++r) {
        int rl = w * 32 + m * 16 + (l >> 4) * 4 + r;
        float v = acc[m][nt][r] + bias[nt];
        Cs[rl * 68 + nt * 16 + (l & 15)] = v;
        if (n0 + rl < NF) { s[nt] += v; q[nt] += v * v; }
      }
#pragma unroll
  for (int nt = 0; nt < 4; ++nt) {
    int idx = (w * 4 + (l >> 4)) * 64 + nt * 16 + (l & 15);
    Ss[idx] = s[nt]; Qs[idx] = q[nt];
  }
  __syncthreads();
  if (node_s < NF) {
    u16* dst = yb + (size_t)node_s * 64 + half * 32;
    const float* cp = Cs + nn * 68 + half * 32;
#pragma unroll
    for (int u = 0; u < 4; ++u) {
      bf16x8 v;
#pragma unroll
      for (int e = 0; e < 8; ++e) v[e] = (short)f2bf(cp[u * 8 + e]);
      *(bf16x8*)(dst + u * 8) = v;
    }
  }
  if (t < 64) {
    float S = 0.f, Q = 0.f;
#pragma unroll
    for (int rr = 0; rr < 16; ++rr) { S += Ss[rr * 64 + t]; Q += Qs[rr * 64 + t]; }
    psum[blockIdx.x * 64 + t] = S;
    psq [blockIdx.x * 64 + t] = Q;
  }
}

// ---------------- K4a: BN partial tree-reduce  [nblk][64] -> [32][64] ----------------
__global__ __launch_bounds__(256) void k_statsA(const float* __restrict__ ps,
                                                const float* __restrict__ pq,
                                                int nblk,
                                                float* __restrict__ os,
                                                float* __restrict__ oq){
  __shared__ float sh[8][64];
  const int t = threadIdx.x, c = t & 63, r = t >> 6;
  float S = 0.f, Q = 0.f;
  for (int b = blockIdx.x * 4 + r; b < nblk; b += 128) { S += ps[b * 64 + c]; Q += pq[b * 64 + c]; }
  sh[r][c] = S; sh[4 + r][c] = Q;
  __syncthreads();
  if (t < 64) {
    os[blockIdx.x * 64 + t] = sh[0][t] + sh[1][t] + sh[2][t] + sh[3][t];
    oq[blockIdx.x * 64 + t] = sh[4][t] + sh[5][t] + sh[6][t] + sh[7][t];
  }
}

// ---------------- K4b: BN stats finalize (reads 32 rows) ----------------
__global__ __launch_bounds__(256) void k_stats(const float* __restrict__ ps,
                                               const float* __restrict__ pq,
                                               int nblk,
                                               const float* __restrict__ g,
                                               const float* __restrict__ beta,
                                               float* __restrict__ st){
  __shared__ float sh[8][64];
  const int t = threadIdx.x, c = t & 63, r = t >> 6;
  float S = 0.f, Q = 0.f;
  for (int b = r; b < nblk; b += 4) { S += ps[b * 64 + c]; Q += pq[b * 64 + c]; }
  sh[r][c] = S; sh[4 + r][c] = Q;
  __syncthreads();
  if (t < 64) {
    float Ss = sh[0][t] + sh[1][t] + sh[2][t] + sh[3][t];
    float Qs = sh[4][t] + sh[5][t] + sh[6][t] + sh[7][t];
    float mean = Ss * (1.f / (float)NF);
    float var  = Qs * (1.f / (float)NF) - mean * mean;
    var = var < 0.f ? 0.f : var;
    float scale = g[t] * rsqrtf(var + EPSV);
    st[t] = scale;
    st[64 + t] = beta[t] - mean * scale;
  }
}

// ---------------- K5: conv2 — BN1+lrelu fused in staging (r4-best), A+B LDS-staged ----------------
// LDS: As [128][72] @0 (18432), Bs [64][72] @18432; Cs [128][68] @0 (post-sync);
// Ss @34816; Qs @38912; Sst [128] f32 @43008. total 43520.
__global__ __launch_bounds__(256) void k_conv2(const u16* __restrict__ yb,
                                               const int* __restrict__ neigh,
                                               const u16* __restrict__ W2b,
                                               const float* __restrict__ b2,
                                               const float* __restrict__ st1,
                                               u16* __restrict__ op,
                                               float* __restrict__ psum,
                                               float* __restrict__ psq){
  __shared__ __align__(16) unsigned char smem[43520];
  u16* As = (u16*)smem;
  u16* Bs = (u16*)(smem + 18432);
  float* Cs = (float*)smem;
  float* Ss = (float*)(smem + 34816);
  float* Qs = (float*)(smem + 38912);
  float* Sst = (float*)(smem + 43008);
  const int t = threadIdx.x, l = t & 63, w = t >> 6;
  const int nn = t >> 1, half = t & 1;
  const int n0 = blockIdx.x * 128;
  const int node_s = n0 + nn;
  if (t < 128) Sst[t] = st1[t];
  f32x4 acc[2][4];
#pragma unroll
  for (int m = 0; m < 2; ++m)
#pragma unroll
    for (int nt = 0; nt < 4; ++nt) { acc[m][nt][0]=0.f; acc[m][nt][1]=0.f; acc[m][nt][2]=0.f; acc[m][nt][3]=0.f; }
  float bias[4];
#pragma unroll
  for (int nt = 0; nt < 4; ++nt) bias[nt] = b2[nt * 16 + (l & 15)];
  for (int j = 0; j < 7; ++j) {
    __syncthreads();
    {
      int r = (node_s < NF) ? neigh[7 * node_s + j] : 0;
      const int4* gp = (const int4*)(yb + (size_t)r * 64 + half * 32);
#pragma unroll
      for (int u = 0; u < 4; ++u) {
        int c8 = half * 4 + u;
        int4 raw = gp[u];
        u16* pr = (u16*)&raw;
        bf16x8 v;
#pragma unroll
        for (int e = 0; e < 8; ++e) {
          float f = bf2f(pr[e]) * Sst[c8 * 8 + e] + Sst[64 + c8 * 8 + e];
          v[e] = (short)f2bf(lrelu(f));
        }
        *(bf16x8*)(As + nn * 72 + c8 * 8) = v;
      }
    }
    {
      int o = t & 63, ci = t >> 6;
      const int4* gp = (const int4*)(W2b + (size_t)o * 448 + j * 64 + ci * 16);
#pragma unroll
      for (int u = 0; u < 2; ++u) *(int4*)(Bs + o * 72 + ci * 16 + u * 8) = gp[u];
    }
    __syncthreads();
    const u16* pA = As + (w * 32 + (l & 15)) * 72 + (l >> 4) * 8;
    const u16* pB = Bs + (l & 15) * 72 + (l >> 4) * 8;
#pragma unroll
    for (int kk = 0; kk < 2; ++kk) {
      bf16x8 a0 = *(const bf16x8*)(pA + kk * 32);
      bf16x8 a1 = *(const bf16x8*)(pA + 16 * 72 + kk * 32);
#pragma unroll
      for (int nt = 0; nt < 4; ++nt) {
        bf16x8 b = *(const bf16x8*)(pB + nt * 16 * 72 + kk * 32);
        acc[0][nt] = MFMA(a0, b, acc[0][nt]);
        acc[1][nt] = MFMA(a1, b, acc[1][nt]);
      }
    }
  }
  __syncthreads();   // all As/Bs reads done before Cs overwrite (cross-wave alias)
  float s[4] = {0.f,0.f,0.f,0.f}, q[4] = {0.f,0.f,0.f,0.f};
#pragma unroll
  for (int m = 0; m < 2; ++m)
#pragma unroll
    for (int nt = 0; nt < 4; ++nt)
#pragma unroll
      for (int r = 0; r < 4; ++r) {
        int rl = w * 32 + m * 16 + (l >> 4) * 4 + r;
        float v = acc[m][nt][r] + bias[nt];
        Cs[rl * 68 + nt * 16 + (l & 15)] = v;
        if (n0 + rl < NF) { s[nt] += v; q[nt] += v * v; }
      }
#pragma unroll
  for (int nt = 0; nt < 4; ++nt) {
    int idx = (w * 4 + (l >> 4)) * 64 + nt * 16 + (l & 15);
    Ss[idx] = s[nt]; Qs[idx] = q[nt];
  }
  __syncthreads();
  if (node_s < NF) {
    u16* dst = op + (size_t)node_s * 64 + half * 32;
    const float* cp = Cs + nn * 68 + half * 32;
#pragma unroll
    for (int u = 0; u < 4; ++u) {
      bf16x8 v;
#pragma unroll
      for (int e = 0; e < 8; ++e) v[e] = (short)f2bf(cp[u * 8 + e]);
      *(bf16x8*)(dst + u * 8) = v;
    }
  }
  if (t < 64) {
    float S = 0.f, Q = 0.f;
#pragma unroll
    for (int rr = 0; rr < 16; ++rr) { S += Ss[rr * 64 + t]; Q += Qs[rr * 64 + t]; }
    psum[blockIdx.x * 64 + t] = S;
    psq [blockIdx.x * 64 + t] = Q;
  }
}

// ---------------- K6: apply BN2 + leaky (op bf16 -> out f32) ----------------
__global__ void k_apply(const u16* __restrict__ op, const float* __restrict__ st2,
                        float* __restrict__ out){
  int gid = blockIdx.x * blockDim.x + threadIdx.x;
  if (gid >= NF * 8) return;
  int q = gid & 7;
  int4 raw = *(const int4*)(op + (size_t)gid * 8);
  const u16* pr = (const u16*)&raw;
  float4 o0, o1;
#pragma unroll
  for (int e = 0; e < 8; ++e) {
    float v = bf2f(pr[e]) * st2[q * 8 + e] + st2[64 + q * 8 + e];
    if (e < 4) (&o0.x)[e] = lrelu(v); else (&o1.x)[e - 4] = lrelu(v);
  }
  float4* dst = (float4*)(out + (size_t)gid * 8);
  dst[0] = o0; dst[1] = o1;
}

extern "C" void kernel_launch(void* const* d_in, const int* in_sizes, int n_in,
                              void* d_out, int out_size, void* d_ws, size_t ws_size,
                              hipStream_t stream) {
  (void)in_sizes; (void)n_in; (void)out_size; (void)ws_size;
  const float* x1   = (const float*)d_in[0];
  const float* x2   = (const float*)d_in[1];
  const int*   topi = (const int*)d_in[2];
  const int*   downi= (const int*)d_in[3];
  const int*   neigh= (const int*)d_in[4];
  const float* Wup  = (const float*)d_in[5];
  const float* bup  = (const float*)d_in[6];
  const float* W1   = (const float*)d_in[7];
  const float* b1   = (const float*)d_in[8];
  const float* g1   = (const float*)d_in[9];
  const float* be1  = (const float*)d_in[10];
  const float* W2   = (const float*)d_in[11];
  const float* b2   = (const float*)d_in[12];
  const float* g2   = (const float*)d_in[13];
  const float* be2  = (const float*)d_in[14];
  float* out = (float*)d_out;

  char* ws = (char*)d_ws;
  u16*   h    = (u16*)(ws);                    // 7NC x 64 bf16 = 36,701,952 B
  u16*   op   = (u16*)(ws);                    // NF x 64 bf16 (aliases h; h dead post build_x)
  u16*   x    = (u16*)(ws + 36701952ull);      // NF x 128 bf16 = 41,943,552 B
  u16*   y    = (u16*)(ws + 78645504ull);      // NF x 64 bf16  = 20,971,776 B
  u16*   Wupb = (u16*)(ws + 99617280ull);      // 448x128 bf16
  u16*   W1b  = (u16*)(ws + 99731968ull);      // 64x896 bf16
  u16*   W2b  = (u16*)(ws + 99846656ull);      // 64x448 bf16
  float* p1s  = (float*)(ws + 99904000ull);    // NBLK*64 f32 = 327,936 B each
  float* p1q  = (float*)(ws + 100231936ull);
  float* p2s  = (float*)(ws + 100559872ull);
  float* p2q  = (float*)(ws + 100887808ull);
  float* st1  = (float*)(ws + 101215744ull);
  float* st2  = (float*)(ws + 101216256ull);
  float* r1s  = (float*)(ws + 101216768ull);   // [32][64] f32
  float* r1q  = (float*)(ws + 101224960ull);
  float* r2s  = (float*)(ws + 101233152ull);
  float* r2q  = (float*)(ws + 101241344ull);

  k_wcvt   <<<70, 256, 0, stream>>>(Wup, Wupb, W1, W1b, W2, W2b);
  k_upconv <<<321 * 7, 256, 0, stream>>>(x1, Wupb, bup, h);
  k_build_x<<<(NF * 16 + 255) / 256, 256, 0, stream>>>(h, x2, topi, downi, x);
  k_conv1  <<<NBLK, 256, 0, stream>>>(x, neigh, W1b, b1, y, p1s, p1q);
  k_statsA <<<32, 256, 0, stream>>>(p1s, p1q, NBLK, r1s, r1q);
  k_stats  <<<1, 256, 0, stream>>>(r1s, r1q, 32, g1, be1, st1);
  k_conv2  <<<NBLK, 256, 0, stream>>>(y, neigh, W2b, b2, st1, op, p2s, p2q);
  k_statsA <<<32, 256, 0, stream>>>(p2s, p2q, NBLK, r2s, r2q);
  k_stats  <<<1, 256, 0, stream>>>(r2s, r2q, 32, g2, be2, st2);
  k_apply  <<<(NF * 8 + 255) / 256, 256, 0, stream>>>(op, st2, out);
}